// Round 1
// baseline (159.672 us; speedup 1.0000x reference)
//
#include <hip/hip_runtime.h>
#include <math.h>

// JPEG luma quantization table [8][8] flattened
__constant__ float c_ytab[64] = {
  16.f,11.f,10.f,16.f,24.f,40.f,51.f,61.f,
  12.f,12.f,14.f,19.f,26.f,58.f,60.f,55.f,
  14.f,13.f,16.f,24.f,40.f,57.f,69.f,56.f,
  14.f,17.f,22.f,29.f,51.f,87.f,80.f,62.f,
  18.f,22.f,37.f,56.f,68.f,109.f,103.f,77.f,
  24.f,35.f,55.f,64.f,81.f,104.f,113.f,92.f,
  49.f,64.f,78.f,87.f,103.f,121.f,120.f,101.f,
  72.f,92.f,95.f,98.f,112.f,100.f,103.f,99.f};

// JPEG chroma quantization table
__constant__ float c_ctab[64] = {
  17.f,18.f,24.f,47.f,99.f,99.f,99.f,99.f,
  18.f,21.f,26.f,66.f,99.f,99.f,99.f,99.f,
  24.f,26.f,56.f,99.f,99.f,99.f,99.f,99.f,
  47.f,66.f,99.f,99.f,99.f,99.f,99.f,99.f,
  99.f,99.f,99.f,99.f,99.f,99.f,99.f,99.f,
  99.f,99.f,99.f,99.f,99.f,99.f,99.f,99.f,
  99.f,99.f,99.f,99.f,99.f,99.f,99.f,99.f,
  99.f,99.f,99.f,99.f,99.f,99.f,99.f,99.f};

// One block = 64x16 pixel tile of one image:
//   -> 16 Y 8x8 blocks (2 rows x 8 cols), 4 Cb + 4 Cr 8x8 blocks (pooled 32x8).
// H=W=512 fixed by the problem; B passed in.
__global__ __launch_bounds__(256) void jpeg_kernel(
    const float* __restrict__ x, const float* __restrict__ factor,
    float* __restrict__ out, int B)
{
    __shared__ float s_y [16][68];   // Y pixels (64 wide, +4 pad)
    __shared__ float s_cb[16][68];
    __shared__ float s_cr[16][68];
    __shared__ float s_cp[2][8][36]; // pooled chroma 8x32 (+4 pad)
    __shared__ float s_ty[16][72];   // Y DCT pass-1 temp: [blk][x*9+v]
    __shared__ float s_tc[2][4][72]; // chroma DCT pass-1 temp
    __shared__ float s_C [8][9];     // cos basis C[y][v] = cos((2y+1)v*pi/16)

    const int t      = threadIdx.x;
    const int b      = blockIdx.x >> 8;    // image index (256 tiles/image)
    const int rem    = blockIdx.x & 255;
    const int tile_y = rem >> 3;           // 0..31 (16-pixel rows)
    const int tile_x = rem & 7;            // 0..7  (64-pixel cols)

    if (t < 64) {
        int yy = t >> 3, vv = t & 7;
        s_C[yy][vv] = cosf((float)((2*yy+1)*vv) * 0.19634954084936207f); // pi/16
    }

    // ---- Phase A: load + RGB->YCbCr, stage to LDS --------------------------
    {
        const int row = t >> 4;            // 0..15
        const int col = (t & 15) << 2;     // 0,4,...,60
        const int gy  = tile_y * 16 + row;
        const int gx  = (tile_x << 6) + col;
        const float* px = x + ((size_t)b * 3 * 512 + gy) * 512 + gx;
        float4 r4 = *(const float4*)(px);
        float4 g4 = *(const float4*)(px + 262144);   // channel 1
        float4 b4 = *(const float4*)(px + 524288);   // channel 2
        float4 yv, cbv, crv;
        #define CC(RR,GG,BB,Y,CB,CR) { \
            float R = (RR)*255.0f, G = (GG)*255.0f, Bl = (BB)*255.0f; \
            (Y)  =  0.299f*R + 0.587f*G + 0.114f*Bl; \
            (CB) = -0.168736f*R - 0.331264f*G + 0.5f*Bl + 128.0f; \
            (CR) =  0.5f*R - 0.418688f*G - 0.081312f*Bl + 128.0f; }
        CC(r4.x, g4.x, b4.x, yv.x, cbv.x, crv.x);
        CC(r4.y, g4.y, b4.y, yv.y, cbv.y, crv.y);
        CC(r4.z, g4.z, b4.z, yv.z, cbv.z, crv.z);
        CC(r4.w, g4.w, b4.w, yv.w, cbv.w, crv.w);
        #undef CC
        *(float4*)&s_y [row][col] = yv;
        *(float4*)&s_cb[row][col] = cbv;
        *(float4*)&s_cr[row][col] = crv;
    }
    __syncthreads();

    // ---- Phase B: 2x2 chroma pooling + Y DCT pass 1 ------------------------
    {
        int ch = t >> 7;                   // 0=cb, 1=cr
        int tt = t & 127;
        const float (*src)[68] = ch ? s_cr : s_cb;
        int pr  = (tt * 2) >> 5;           // pooled row 0..7
        int pc0 = (tt * 2) & 31;
        #pragma unroll
        for (int k = 0; k < 2; ++k) {
            int pc = pc0 + k;
            s_cp[ch][pr][pc] = 0.25f * (src[2*pr][2*pc]   + src[2*pr][2*pc+1] +
                                        src[2*pr+1][2*pc] + src[2*pr+1][2*pc+1]);
        }
    }
    {
        int e   = t << 2;                  // 4 of 1024 tmp elements
        int blk = e >> 6;                  // 0..15
        int xx  = (e >> 3) & 7;
        int v0  = e & 7;                   // 0 or 4
        int by = blk >> 3, bx = blk & 7;
        const float* ar = &s_y[by*8 + xx][bx*8];
        float a[8];
        #pragma unroll
        for (int j = 0; j < 8; ++j) a[j] = ar[j] - 128.0f;
        #pragma unroll
        for (int k = 0; k < 4; ++k) {
            int v = v0 + k;
            float s = 0.f;
            #pragma unroll
            for (int j = 0; j < 8; ++j) s += a[j] * s_C[j][v];
            s_ty[blk][xx*9 + v] = s;
        }
    }
    __syncthreads();

    const float f = factor[b];

    // ---- Phase C: chroma DCT pass 1 + Y pass 2 / quantize / store ----------
    {
        int ch = t >> 7;
        int tt = t & 127;
        int e   = tt << 1;                 // 2 of 256 tmp elements per channel
        int blk = e >> 6;                  // 0..3
        int xx  = (e >> 3) & 7;
        int v0  = e & 7;                   // 0,2,4,6
        const float* ar = &s_cp[ch][xx][blk*8];
        float a[8];
        #pragma unroll
        for (int j = 0; j < 8; ++j) a[j] = ar[j] - 128.0f;
        #pragma unroll
        for (int k = 0; k < 2; ++k) {
            int v = v0 + k;
            float s = 0.f;
            #pragma unroll
            for (int j = 0; j < 8; ++j) s += a[j] * s_C[j][v];
            s_tc[ch][blk][xx*9 + v] = s;
        }
    }
    {
        int e   = t << 2;                  // 4 of 1024 Y outputs
        int blk = e >> 6;
        int u   = (e >> 3) & 7;
        int v0  = e & 7;                   // 0 or 4
        int by = blk >> 3, bx = blk & 7;
        float au = (u == 0) ? 0.70710678118654752f : 1.0f;
        float4 res;
        float* rp = (float*)&res;
        #pragma unroll
        for (int k = 0; k < 4; ++k) {
            int v = v0 + k;
            float s = 0.f;
            #pragma unroll
            for (int j = 0; j < 8; ++j) s += s_C[j][u] * s_ty[blk][j*9 + v];
            float av   = (v == 0) ? 0.70710678118654752f : 1.0f;
            float coef = s * (au * av * 0.25f);
            float q    = coef / (c_ytab[u*8 + v] * f);
            float r    = rintf(q);          // round-half-even, matches jnp.round
            float d    = q - r;
            rp[k] = r + d * d * d;          // diff_round
        }
        size_t n = (size_t)b * 4096 + (size_t)(tile_y*2 + by) * 64 + (tile_x*8 + bx);
        *(float4*)(out + n * 64 + u*8 + v0) = res;
    }
    __syncthreads();

    // ---- Phase D: chroma pass 2 / quantize / store -------------------------
    {
        int ch  = t >> 7;
        int tt  = t & 127;
        int e   = tt << 1;                 // 2 of 256 outputs per channel
        int blk = e >> 6;                  // 0..3
        int u   = (e >> 3) & 7;
        int v0  = e & 7;                   // 0,2,4,6
        float au = (u == 0) ? 0.70710678118654752f : 1.0f;
        float2 res;
        float* rp = (float*)&res;
        #pragma unroll
        for (int k = 0; k < 2; ++k) {
            int v = v0 + k;
            float s = 0.f;
            #pragma unroll
            for (int j = 0; j < 8; ++j) s += s_C[j][u] * s_tc[ch][blk][j*9 + v];
            float av   = (v == 0) ? 0.70710678118654752f : 1.0f;
            float coef = s * (au * av * 0.25f);
            float q    = coef / (c_ctab[u*8 + v] * f);
            float r    = rintf(q);
            float d    = q - r;
            rp[k] = r + d * d * d;
        }
        // cb region starts at B*4096*64, cr after another B*1024*64
        size_t base = (size_t)B * 262144 + (size_t)ch * (size_t)B * 65536;
        size_t n    = (size_t)b * 1024 + tile_y * 32 + tile_x * 4 + blk;
        *(float2*)(out + base + n * 64 + u*8 + v0) = res;
    }
}

extern "C" void kernel_launch(void* const* d_in, const int* in_sizes, int n_in,
                              void* d_out, int out_size, void* d_ws, size_t ws_size,
                              hipStream_t stream) {
    const float* x      = (const float*)d_in[0];
    const float* factor = (const float*)d_in[1];
    float* out          = (float*)d_out;
    const int B = in_sizes[1];             // factor has one element per image
    dim3 grid(B * 256), block(256);
    jpeg_kernel<<<grid, block, 0, stream>>>(x, factor, out, B);
}